// Round 1
// baseline (1131.816 us; speedup 1.0000x reference)
//
#include <hip/hip_runtime.h>

#define N_NODES 10000
#define N_EDGES 640000
#define D_FEAT 128

// 32 threads per edge; each thread handles 4 consecutive floats (float4).
// Gather x[src] row (coalesced 512B), atomicAdd into out[dst] row.
__global__ __launch_bounds__(256) void scatter_add_kernel(
    const float* __restrict__ x,
    const int* __restrict__ src,
    const int* __restrict__ dst,
    float* __restrict__ out) {
    long long gid = (long long)blockIdx.x * blockDim.x + threadIdx.x;
    int e = (int)(gid >> 5);
    if (e >= N_EDGES) return;
    int f = ((int)gid & 31) << 2;  // feature offset 0..124 step 4

    int s = src[e];
    int d = dst[e];

    const float4 v = *reinterpret_cast<const float4*>(&x[(size_t)s * D_FEAT + f]);
    float* o = &out[(size_t)d * D_FEAT + f];
    atomicAdd(o + 0, v.x);
    atomicAdd(o + 1, v.y);
    atomicAdd(o + 2, v.z);
    atomicAdd(o + 3, v.w);
}

// out[node][f] /= deg[node], vectorized as float4
__global__ __launch_bounds__(256) void normalize_kernel(
    float* __restrict__ out, const float* __restrict__ deg) {
    int gid = blockIdx.x * blockDim.x + threadIdx.x;
    const int total = N_NODES * (D_FEAT / 4);
    if (gid >= total) return;
    int node = gid / (D_FEAT / 4);
    float inv = 1.0f / deg[node];
    float4* p = reinterpret_cast<float4*>(out) + gid;
    float4 v = *p;
    v.x *= inv; v.y *= inv; v.z *= inv; v.w *= inv;
    *p = v;
}

extern "C" void kernel_launch(void* const* d_in, const int* in_sizes, int n_in,
                              void* d_out, int out_size, void* d_ws, size_t ws_size,
                              hipStream_t stream) {
    const float* x   = (const float*)d_in[0];
    const int*   ei  = (const int*)d_in[1];   // [2, N_EDGES] flat: src row, dst row
    const float* deg = (const float*)d_in[2];
    float* out = (float*)d_out;

    const int* src = ei;
    const int* dst = ei + N_EDGES;

    // Zero the accumulator (d_out is re-poisoned to 0xAA before each launch).
    hipMemsetAsync(d_out, 0, (size_t)out_size * sizeof(float), stream);

    // Scatter-add: 32 threads/edge
    {
        long long total_threads = (long long)N_EDGES * 32;
        int block = 256;
        long long grid = (total_threads + block - 1) / block;
        scatter_add_kernel<<<(int)grid, block, 0, stream>>>(x, src, dst, out);
    }

    // Normalize by degree
    {
        int total = N_NODES * (D_FEAT / 4);
        int block = 256;
        int grid = (total + block - 1) / block;
        normalize_kernel<<<grid, block, 0, stream>>>(out, deg);
    }
}

// Round 2
// 186.603 us; speedup vs baseline: 6.0654x; 6.0654x over previous
//
#include <hip/hip_runtime.h>

#define N_NODES 10000
#define N_EDGES 640000
#define D_FEAT 128
#define SCAN_BLOCK 1024

// ---- ws layout (bytes) ----
// counts  : [0, 40000)                 int[10000]
// offsets : [40064, 80068)             int[10001]
// cursors : [80128, 120128)            int[10000]
// csr_src : [120192, 2680192)          int[640000]
#define WS_COUNTS 0
#define WS_OFFSETS 40064
#define WS_CURSORS 80128
#define WS_CSR 120192

__global__ __launch_bounds__(256) void hist_kernel(
    const int* __restrict__ dst, int* __restrict__ counts) {
    int e = blockIdx.x * blockDim.x + threadIdx.x;
    if (e < N_EDGES) atomicAdd(&counts[dst[e]], 1);
}

// Single-block exclusive scan over counts -> offsets (and a copy into cursors).
__global__ __launch_bounds__(SCAN_BLOCK) void scan_kernel(
    const int* __restrict__ counts, int* __restrict__ offsets,
    int* __restrict__ cursors) {
    __shared__ int lds[SCAN_BLOCK];
    __shared__ int running_s;
    int tid = threadIdx.x;
    if (tid == 0) running_s = 0;
    __syncthreads();
    const int nchunk = (N_NODES + SCAN_BLOCK - 1) / SCAN_BLOCK;
    for (int c = 0; c < nchunk; ++c) {
        int i = c * SCAN_BLOCK + tid;
        int v = (i < N_NODES) ? counts[i] : 0;
        lds[tid] = v;
        __syncthreads();
        for (int off = 1; off < SCAN_BLOCK; off <<= 1) {
            int t = (tid >= off) ? lds[tid - off] : 0;
            __syncthreads();
            lds[tid] += t;
            __syncthreads();
        }
        int incl = lds[tid];
        int base = running_s;               // stable: updated only after next barrier
        if (i < N_NODES) {
            int o = base + incl - v;        // exclusive
            offsets[i] = o;
            cursors[i] = o;
        }
        int total = lds[SCAN_BLOCK - 1];
        __syncthreads();
        if (tid == 0) running_s = base + total;
        __syncthreads();
    }
    if (tid == 0) offsets[N_NODES] = running_s;
}

__global__ __launch_bounds__(256) void fill_kernel(
    const int* __restrict__ src, const int* __restrict__ dst,
    int* __restrict__ cursors, int* __restrict__ csr_src) {
    int e = blockIdx.x * blockDim.x + threadIdx.x;
    if (e < N_EDGES) {
        int pos = atomicAdd(&cursors[dst[e]], 1);
        csr_src[pos] = src[e];
    }
}

// 32 lanes per node; lane handles float4 of the 128-wide feature row.
// Sum x[src] rows over the node's in-edges in registers, normalize, one store.
__global__ __launch_bounds__(256) void gather_kernel(
    const float* __restrict__ x, const int* __restrict__ offsets,
    const int* __restrict__ csr_src, const float* __restrict__ deg,
    float* __restrict__ out) {
    int gid = blockIdx.x * blockDim.x + threadIdx.x;
    int node = gid >> 5;
    if (node >= N_NODES) return;
    int f = (gid & 31) << 2;

    int start = offsets[node];
    int end = offsets[node + 1];

    float4 acc = make_float4(0.f, 0.f, 0.f, 0.f);
    int j = start;
    // Unroll by 4 for memory-level parallelism.
    for (; j + 4 <= end; j += 4) {
        int s0 = csr_src[j + 0];
        int s1 = csr_src[j + 1];
        int s2 = csr_src[j + 2];
        int s3 = csr_src[j + 3];
        float4 a = *reinterpret_cast<const float4*>(&x[(size_t)s0 * D_FEAT + f]);
        float4 b = *reinterpret_cast<const float4*>(&x[(size_t)s1 * D_FEAT + f]);
        float4 c = *reinterpret_cast<const float4*>(&x[(size_t)s2 * D_FEAT + f]);
        float4 d = *reinterpret_cast<const float4*>(&x[(size_t)s3 * D_FEAT + f]);
        acc.x += a.x + b.x + c.x + d.x;
        acc.y += a.y + b.y + c.y + d.y;
        acc.z += a.z + b.z + c.z + d.z;
        acc.w += a.w + b.w + c.w + d.w;
    }
    for (; j < end; ++j) {
        int s = csr_src[j];
        float4 a = *reinterpret_cast<const float4*>(&x[(size_t)s * D_FEAT + f]);
        acc.x += a.x; acc.y += a.y; acc.z += a.z; acc.w += a.w;
    }

    float inv = 1.0f / deg[node];
    float4 r = make_float4(acc.x * inv, acc.y * inv, acc.z * inv, acc.w * inv);
    *reinterpret_cast<float4*>(&out[(size_t)node * D_FEAT + f]) = r;
}

extern "C" void kernel_launch(void* const* d_in, const int* in_sizes, int n_in,
                              void* d_out, int out_size, void* d_ws, size_t ws_size,
                              hipStream_t stream) {
    const float* x   = (const float*)d_in[0];
    const int*   ei  = (const int*)d_in[1];   // [2, N_EDGES] flat: src row, dst row
    const float* deg = (const float*)d_in[2];
    float* out = (float*)d_out;

    const int* src = ei;
    const int* dst = ei + N_EDGES;

    char* ws = (char*)d_ws;
    int* counts  = (int*)(ws + WS_COUNTS);
    int* offsets = (int*)(ws + WS_OFFSETS);
    int* cursors = (int*)(ws + WS_CURSORS);
    int* csr_src = (int*)(ws + WS_CSR);

    // Zero histogram counters (ws is poisoned 0xAA each call).
    hipMemsetAsync(counts, 0, N_NODES * sizeof(int), stream);

    const int block = 256;
    const int egrid = (N_EDGES + block - 1) / block;

    hist_kernel<<<egrid, block, 0, stream>>>(dst, counts);
    scan_kernel<<<1, SCAN_BLOCK, 0, stream>>>(counts, offsets, cursors);
    fill_kernel<<<egrid, block, 0, stream>>>(src, dst, cursors, csr_src);

    {
        long long total_threads = (long long)N_NODES * 32;
        int grid = (int)((total_threads + block - 1) / block);
        gather_kernel<<<grid, block, 0, stream>>>(x, offsets, csr_src, deg, out);
    }
}